// Round 3
// baseline (739.685 us; speedup 1.0000x reference)
//
#include <hip/hip_runtime.h>

// DockBoardAttention: B=65536, NDOCK=3, DCELL=25, C=32, HW=64, HD=16
// R3: TWO batches per wave, explicitly software-pipelined with counted vmcnt.
//   issue DMA(b0)+DMA(b1) up front -> A-phases (both) under the stream ->
//   vmcnt(8): compute b0 while b1 streams -> vmcnt(0) -> store out0 -> compute b1.
// One wave still owns its batches end-to-end; no barriers; all LDS wave-private.
//
// Algebra: sc[n][s] = sum_c A[n][c] g[c][s],  A = k*(dock@Wq^T + bq)@Wk  (q.bk cancels in softmax)
//          out[n][e] = (sum_c U[e][c] z'[n][c]) / D[n] + c0[e]
//          z'[n][c] = sum_s e[n][s] g[c][s],  e = exp2(sc) (no max-sub: |sc| <~ 2),  D[n] = sum_s e[n][s]
//          U = Wo@Wv, c0 = Wo@bv + bo;  k = 0.25*log2(e) folded into A.
//
// g staging swizzle (m173 pattern, verified R2): granule (c,s4) -> LDS slot 16*c + (s4^(c&15));
//   scores read word 64*c + (lane ^ (4*(c&15))); z reads float4 at 64*c + 4*(j^(c&15)).

#define NW 4

// ws layout (floats): M[25*32] @0, bkt[32] @800, U[16*32] @832, c0[16] @1344
__global__ void precompute_kernel(const float* __restrict__ Wq, const float* __restrict__ bq,
                                  const float* __restrict__ Wk, const float* __restrict__ Wv,
                                  const float* __restrict__ bv, const float* __restrict__ Wo,
                                  const float* __restrict__ bo, float* __restrict__ ws)
{
    const float K = 0.25f * 1.44269504088896f;
    const int t = threadIdx.x;
    for (int i = t; i < 800; i += 256) {           // M~[j][c] = K * sum_d Wq[d][j]*Wk[d][c]
        int j = i >> 5, c = i & 31;
        float s = 0.f;
        #pragma unroll
        for (int d = 0; d < 16; ++d) s += Wq[d * 25 + j] * Wk[d * 32 + c];
        ws[i] = s * K;
    }
    if (t < 32) {                                   // bkt~[c] = K * sum_d bq[d]*Wk[d][c]
        float s = 0.f;
        #pragma unroll
        for (int d = 0; d < 16; ++d) s += bq[d] * Wk[d * 32 + t];
        ws[800 + t] = s * K;
    }
    for (int i = t; i < 512; i += 256) {            // U[e][c] = sum_d Wo[e][d]*Wv[d][c]
        int e = i >> 5, c = i & 31;
        float s = 0.f;
        #pragma unroll
        for (int d = 0; d < 16; ++d) s += Wo[e * 16 + d] * Wv[d * 32 + c];
        ws[832 + i] = s;
    }
    if (t < 16) {                                   // c0[e] = sum_d Wo[e][d]*bv[d] + bo[e]
        float s = bo[t];
        #pragma unroll
        for (int d = 0; d < 16; ++d) s += Wo[t * 16 + d] * bv[d];
        ws[1344 + t] = s;
    }
}

__device__ __forceinline__ float rl(float v, int srclane) {
    return __int_as_float(__builtin_amdgcn_readlane(__float_as_int(v), srclane));
}

__device__ __forceinline__ void gload_lds16(const float* src, float* dst_lds) {
    __builtin_amdgcn_global_load_lds(
        (const __attribute__((address_space(1))) void*)src,
        (__attribute__((address_space(3))) void*)dst_lds, 16, 0, 0);
}

// Full per-batch pipeline after its gT tile is LDS-resident and AL is written.
// Returns the out value for lanes 0..47 (undefined elsewhere). attnL/zL reused
// across batches (wave-private, in-order LDS per wave -> compiler tracks deps).
__device__ __forceinline__ float batch_compute(const float* __restrict__ gTw,
                                               const float* __restrict__ ALw,
                                               float* __restrict__ attnLw,
                                               float* __restrict__ zLw,
                                               const float* __restrict__ Ug,
                                               const float* __restrict__ c0,
                                               int lane)
{
    // ---- scores: sc[n] = sum_c A[n][c]*g[c][lane] ----
    float sc0 = 0.f, sc1 = 0.f, sc2 = 0.f;
    {
        const float4* A4 = (const float4*)ALw;
        #pragma unroll
        for (int qq = 0; qq < 8; ++qq) {
            float4 a = A4[qq], bb = A4[8 + qq], cc = A4[16 + qq];
            const int c = 4 * qq;
            float g0 = gTw[((c + 0) << 6) + (lane ^ (((c + 0) & 15) << 2))];
            float g1 = gTw[((c + 1) << 6) + (lane ^ (((c + 1) & 15) << 2))];
            float g2 = gTw[((c + 2) << 6) + (lane ^ (((c + 2) & 15) << 2))];
            float g3 = gTw[((c + 3) << 6) + (lane ^ (((c + 3) & 15) << 2))];
            sc0 = fmaf(a.x, g0, fmaf(a.y, g1, fmaf(a.z, g2, fmaf(a.w, g3, sc0))));
            sc1 = fmaf(bb.x, g0, fmaf(bb.y, g1, fmaf(bb.z, g2, fmaf(bb.w, g3, sc1))));
            sc2 = fmaf(cc.x, g0, fmaf(cc.y, g1, fmaf(cc.z, g2, fmaf(cc.w, g3, sc2))));
        }
    }

    // ---- unnormalized numerators (|sc| <~ 2 in exp2 domain -> no max-sub) ----
    attnLw[lane]       = exp2f(sc0);
    attnLw[64 + lane]  = exp2f(sc1);
    attnLw[128 + lane] = exp2f(sc2);

    // ---- z'[n][c] pass 1: n = lane>>5, c = lane&31 ----
    {
        const int n = lane >> 5, c = lane & 31, cx = c & 15;
        const float4* ar = (const float4*)&attnLw[n * 64];
        const float* grow = &gTw[c << 6];
        float ax = 0.f, ay = 0.f, az = 0.f, aw = 0.f;
        #pragma unroll
        for (int j = 0; j < 16; ++j) {
            float4 a  = ar[j];
            float4 gg = *(const float4*)&grow[(j ^ cx) << 2];
            ax = fmaf(a.x, gg.x, ax);
            ay = fmaf(a.y, gg.y, ay);
            az = fmaf(a.z, gg.z, az);
            aw = fmaf(a.w, gg.w, aw);
        }
        zLw[n * 32 + c] = (ax + ay) + (az + aw);
    }
    // ---- pass 2: lanes 0..31 -> n = 2; lanes 32..34 -> D[n] ----
    if (lane < 32) {
        const int cx = lane & 15;
        const float4* ar = (const float4*)&attnLw[128];
        const float* grow = &gTw[lane << 6];
        float ax = 0.f, ay = 0.f, az = 0.f, aw = 0.f;
        #pragma unroll
        for (int j = 0; j < 16; ++j) {
            float4 a  = ar[j];
            float4 gg = *(const float4*)&grow[(j ^ cx) << 2];
            ax = fmaf(a.x, gg.x, ax);
            ay = fmaf(a.y, gg.y, ay);
            az = fmaf(a.z, gg.z, az);
            aw = fmaf(a.w, gg.w, aw);
        }
        zLw[64 + lane] = (ax + ay) + (az + aw);
    } else if (lane < 35) {
        const float4* ar = (const float4*)&attnLw[(lane - 32) * 64];
        float s0 = 0.f, s1 = 0.f, s2 = 0.f, s3 = 0.f;
        #pragma unroll
        for (int j = 0; j < 16; ++j) {
            float4 a = ar[j];
            s0 += a.x; s1 += a.y; s2 += a.z; s3 += a.w;
        }
        zLw[96 + (lane - 32)] = (s0 + s1) + (s2 + s3);
    }

    // ---- out value for lanes 0..47 ----
    float o = 0.f;
    if (lane < 48) {
        const int n = lane >> 4, e = lane & 15;
        const float4* Ur = (const float4*)(Ug + e * 32);
        const float4* zr = (const float4*)&zLw[n * 32];
        float dinv = __builtin_amdgcn_rcpf(zLw[96 + n]);
        float acc0 = 0.f, acc1 = 0.f, acc2 = 0.f, acc3 = 0.f;
        #pragma unroll
        for (int qq = 0; qq < 8; ++qq) {
            float4 u = Ur[qq], z = zr[qq];
            acc0 = fmaf(u.x, z.x, acc0);
            acc1 = fmaf(u.y, z.y, acc1);
            acc2 = fmaf(u.z, z.z, acc2);
            acc3 = fmaf(u.w, z.w, acc3);
        }
        o = fmaf((acc0 + acc1) + (acc2 + acc3), dinv, c0[e]);
    }
    return o;
}

__global__ __launch_bounds__(256, 2) void dock_attn_kernel(
    const float* __restrict__ dock,   // [B,3,25]
    const float* __restrict__ grid,   // [B,32,64]
    const float* __restrict__ ws,     // precomputed M,bkt,U,c0
    float* __restrict__ out,          // [B,48]
    int b_total)
{
    __shared__ __align__(16) float gT[NW][2][2048];  // swizzled g, 8 KB per batch
    __shared__ __align__(16) float AL[NW][2][96];    // A[n][c] per batch
    __shared__ __align__(16) float attnL[NW][192];   // reused b0->b1 (wave-private, in-order)
    __shared__ __align__(16) float zL[NW][104];      // reused b0->b1

    const int tid = threadIdx.x;
    const int w = tid >> 6, lane = tid & 63;
    const int b0 = (blockIdx.x * NW + w) * 2;
    if (b0 >= b_total) return;         // never taken (B%8==0); no barriers so safe

    const float* Mg  = ws;
    const float* bkt = ws + 800;
    const float* Ug  = ws + 832;
    const float* c0  = ws + 1344;

    // ---- scalar loads FIRST (vmcnt is in-order): M/bkt regs + both docks ----
    float mreg[25];
    float bi = 0.f;
    if (lane < 32) {
        #pragma unroll
        for (int j = 0; j < 25; ++j) mreg[j] = Mg[j * 32 + lane];   // L1-hot
        bi = bkt[lane];
    }
    // 150 dock floats for the batch pair in 3 coalesced loads
    const float* dkb = dock + (size_t)b0 * 75;
    float e0 = dkb[lane];                               // idx 0..63
    float e1 = dkb[64 + lane];                          // idx 64..127
    float e2 = (lane < 22) ? dkb[128 + lane] : 0.f;     // idx 128..149

    asm volatile("" ::: "memory");   // pin issue order: scalars before the DMA streams

    // ---- async g stage: 2 batches x 8 x 1KB global->LDS (16 in flight) ----
    {
        const float* gb0 = grid + (size_t)b0 * 2048;
        const int h = lane >> 4, q = lane & 15;
        #pragma unroll
        for (int i = 0; i < 8; ++i) {
            const int c = 4 * i + h;
            const int s4 = q ^ (c & 15);
            gload_lds16(gb0 + c * 64 + 4 * s4, &gT[w][0][i * 256]);
        }
        #pragma unroll
        for (int i = 0; i < 8; ++i) {
            const int c = 4 * i + h;
            const int s4 = q ^ (c & 15);
            gload_lds16(gb0 + 2048 + c * 64 + 4 * s4, &gT[w][1][i * 256]);
        }
    }

    // ---- A-phases for BOTH batches (need only dock/M regs; run under the stream) ----
    if (lane < 32) {
        // batch 0: dock idx j, 25+j, 50+j
        float a0 = bi, a1 = bi, a2 = bi;
        // batch 1: dock idx 75+j, 100+j, 125+j
        float b0a = bi, b1a = bi, b2a = bi;
        #pragma unroll
        for (int j = 0; j < 25; ++j) {
            float m = mreg[j];
            float q0 = rl(e0, j);
            float q1 = rl(e0, 25 + j);                                   // 25+j <= 49
            float q2 = (j < 14) ? rl(e0, 50 + j) : rl(e1, j - 14);       // 50+j
            a0 = fmaf(q0, m, a0);
            a1 = fmaf(q1, m, a1);
            a2 = fmaf(q2, m, a2);
            float p0 = rl(e1, 11 + j);                                   // 75+j
            float p1 = rl(e1, 36 + j);                                   // 100+j
            float p2 = (j < 3) ? rl(e1, 61 + j) : rl(e2, j - 3);         // 125+j
            b0a = fmaf(p0, m, b0a);
            b1a = fmaf(p1, m, b1a);
            b2a = fmaf(p2, m, b2a);
        }
        AL[w][0][lane] = a0; AL[w][0][32 + lane] = a1; AL[w][0][64 + lane] = a2;
        AL[w][1][lane] = b0a; AL[w][1][32 + lane] = b1a; AL[w][1][64 + lane] = b2a;
    }

    // ---- batch 0: gate on its 8 DMAs only; batch 1's stream stays in flight ----
    asm volatile("s_waitcnt vmcnt(8)" ::: "memory");
    float o0 = batch_compute(&gT[w][0][0], &AL[w][0][0], attnL[w], zL[w], Ug, c0, lane);

    // ---- batch 1 tile resident (no stores issued yet -> only DMAs outstanding) ----
    asm volatile("s_waitcnt vmcnt(0)" ::: "memory");
    if (lane < 48) out[(size_t)b0 * 48 + lane] = o0;     // store overlaps b1 compute

    float o1 = batch_compute(&gT[w][1][0], &AL[w][1][0], attnL[w], zL[w], Ug, c0, lane);
    if (lane < 48) out[(size_t)(b0 + 1) * 48 + lane] = o1;
}

extern "C" void kernel_launch(void* const* d_in, const int* in_sizes, int n_in,
                              void* d_out, int out_size, void* d_ws, size_t ws_size,
                              hipStream_t stream) {
    const float* dock = (const float*)d_in[0];
    const float* grid = (const float*)d_in[1];
    const float* Wq   = (const float*)d_in[2];
    const float* bq   = (const float*)d_in[3];
    const float* Wk   = (const float*)d_in[4];
    // d_in[5] = bk: q.bk is constant over spatial axis -> cancels in softmax; unused
    const float* Wv   = (const float*)d_in[6];
    const float* bv   = (const float*)d_in[7];
    const float* Wo   = (const float*)d_in[8];
    const float* bo   = (const float*)d_in[9];
    float* out = (float*)d_out;
    float* ws  = (float*)d_ws;

    precompute_kernel<<<1, 256, 0, stream>>>(Wq, bq, Wk, Wv, bv, Wo, bo, ws);

    const int b_total = in_sizes[0] / 75;   // 65536
    const int blocks = (b_total + 2 * NW - 1) / (2 * NW);   // 8192
    dock_attn_kernel<<<blocks, 256, 0, stream>>>(dock, grid, ws, out, b_total);
}